// Round 6
// baseline (345.575 us; speedup 1.0000x reference)
//
#include <hip/hip_runtime.h>
#include <hip/hip_cooperative_groups.h>
#include <math.h>

namespace cg = cooperative_groups;

#define N_PIX (1024 * 1024)
#define NSEG 1024
#define NCH 32
#define NCHUNK 8
#define NEDGE 8192
#define EPS 1e-8f
#define INV_TAU 2.0f
// Fixed-point scale for int32 LDS histogram accumulation (round-4/5 verified:
// absmax 0.0 vs ref). Native ds_add_u32; float atomicAdd/unsafeAtomicAdd both
// lower to a serialized CAS path (rounds 1-3 A/B: 336us, VALUBusy 0.5%).
#define SCALE 262144.0f
#define INV_SCALE (1.0f / 262144.0f)

// ws layout (4-byte units). Every region fully written before read each
// launch (plain stores only) -> no memset needed, fully deterministic.
#define OFF_GSUMI 0                                  // int  [8][32][1024]
#define OFF_GCNTI (OFF_GSUMI + NCHUNK * NCH * NSEG)  // int  [8][32][1024]
#define OFF_MEANSN (OFF_GCNTI + NCHUNK * NCH * NSEG) // float[1024][32] normalized means
#define OFF_BPE (OFF_MEANSN + NSEG * NCH)            // float[256]
#define OFF_BPI (OFF_BPE + 256)                      // float[256]
#define OFF_IPE (OFF_BPI + 256)                      // float[8]

// ---------------------------------------------------------------------------
// Single fused cooperative kernel. 256 blocks x 1024 threads = exactly one
// block per CU (trivially co-resident). Phases separated by grid.sync():
//  1. segment sums: int fixed-point LDS histogram, layout identical to the
//     verified round-4 k_segsum (c=bid>>3 channel, j=bid&7 pixel chunk;
//     count duty it==c so each pixel is counted exactly once).
//  2. means: block b -> segments 4b..4b+3; thread (s,c) sums 8 chunk
//     partials, 32-lane butterflies for count and norm; writes normalized
//     means (coalesced: meansn[bid*128+t]).
//  3. intra: 4 px/thread, float4 emb loads, meansn row gathers (L2-hot),
//     per-block partial -> bpe/bpi.
//  4. inter: blocks 0..7, edge e=bid*1024+t -> ipe.
//  5. final: block 0 reduces partials -> out.
// ---------------------------------------------------------------------------
__global__ __launch_bounds__(1024) void k_fused(const float* __restrict__ emb,
                                                const int* __restrict__ seg,
                                                const int* __restrict__ edges,
                                                int* __restrict__ gsum_i,
                                                int* __restrict__ gcnt_i,
                                                float* __restrict__ meansn,
                                                float* __restrict__ bpe,
                                                float* __restrict__ bpi,
                                                float* __restrict__ ipe,
                                                float* __restrict__ out) {
    cg::grid_group grid = cg::this_grid();
    __shared__ int lsum[NSEG];
    __shared__ int lcnt[NSEG];
    __shared__ float we[16], wi[16];
    const int bid = blockIdx.x;
    const int t = threadIdx.x;

    // ---------------- phase 1: per-segment sums ----------------
    {
        const int c = bid >> 3;  // channel 0..31
        const int j = bid & 7;   // pixel chunk 0..7
        lsum[t] = 0;
        lcnt[t] = 0;
        __syncthreads();

        const int chunk = N_PIX / NCHUNK;  // 131072 px
        const float* ec = emb + (size_t)c * N_PIX + (size_t)j * chunk;
        const int* sg = seg + j * chunk;

        for (int it = 0; it < chunk / (1024 * 4); ++it) {  // 32 iters
            const int idx = (it * 1024 + t) * 4;
            const float4 v = *(const float4*)(ec + idx);
            const int4 s4 = *(const int4*)(sg + idx);
            atomicAdd(&lsum[s4.x], __float2int_rn(v.x * SCALE));
            atomicAdd(&lsum[s4.y], __float2int_rn(v.y * SCALE));
            atomicAdd(&lsum[s4.z], __float2int_rn(v.z * SCALE));
            atomicAdd(&lsum[s4.w], __float2int_rn(v.w * SCALE));
            if (it == c) {  // each pixel counted exactly once across blocks
                atomicAdd(&lcnt[s4.x], 1);
                atomicAdd(&lcnt[s4.y], 1);
                atomicAdd(&lcnt[s4.z], 1);
                atomicAdd(&lcnt[s4.w], 1);
            }
        }
        __syncthreads();
        gsum_i[(j * NCH + c) * NSEG + t] = lsum[t];
        gcnt_i[(j * NCH + c) * NSEG + t] = lcnt[t];
    }
    grid.sync();

    // ---------------- phase 2: normalized means ----------------
    if (t < 128) {
        const int sl = t >> 5;   // 0..3
        const int cc = t & 31;   // channel
        const int s = bid * 4 + sl;
        int cn = 0, a = 0;
#pragma unroll
        for (int jj = 0; jj < NCHUNK; ++jj) {
            cn += gcnt_i[(jj * NCH + cc) * NSEG + s];
            a += gsum_i[(jj * NCH + cc) * NSEG + s];
        }
        // 32-lane butterflies (stay within each 32-half of the 64-wide wave)
#pragma unroll
        for (int m = 1; m < 32; m <<= 1) cn += __shfl_xor(cn, m);
        const float mval = (float)a * INV_SCALE / fmaxf((float)cn, 1.0f);
        float nm = mval * mval;
#pragma unroll
        for (int m = 1; m < 32; m <<= 1) nm += __shfl_xor(nm, m);
        const float rn = 1.0f / fmaxf(sqrtf(nm), EPS);
        meansn[bid * 128 + t] = mval * rn;  // coalesced: == meansn[s*32+cc]
    }
    grid.sync();

    // ---------------- phase 3: intra ----------------
    {
        const int n0 = (bid * 1024 + t) * 4;
        const int4 s4 = *(const int4*)(seg + n0);

        float dot0 = 0.f, dot1 = 0.f, dot2 = 0.f, dot3 = 0.f;
        float nr0 = 0.f, nr1 = 0.f, nr2 = 0.f, nr3 = 0.f;

#pragma unroll
        for (int c0 = 0; c0 < NCH; c0 += 4) {
            const float4 e0 = *(const float4*)(emb + (size_t)(c0 + 0) * N_PIX + n0);
            const float4 e1 = *(const float4*)(emb + (size_t)(c0 + 1) * N_PIX + n0);
            const float4 e2 = *(const float4*)(emb + (size_t)(c0 + 2) * N_PIX + n0);
            const float4 e3 = *(const float4*)(emb + (size_t)(c0 + 3) * N_PIX + n0);
            const float4 m0 = *(const float4*)(meansn + s4.x * NCH + c0);
            const float4 m1 = *(const float4*)(meansn + s4.y * NCH + c0);
            const float4 m2 = *(const float4*)(meansn + s4.z * NCH + c0);
            const float4 m3 = *(const float4*)(meansn + s4.w * NCH + c0);

            dot0 += m0.x * e0.x + m0.y * e1.x + m0.z * e2.x + m0.w * e3.x;
            dot1 += m1.x * e0.y + m1.y * e1.y + m1.z * e2.y + m1.w * e3.y;
            dot2 += m2.x * e0.z + m2.y * e1.z + m2.z * e2.z + m2.w * e3.z;
            dot3 += m3.x * e0.w + m3.y * e1.w + m3.z * e2.w + m3.w * e3.w;

            nr0 += e0.x * e0.x + e1.x * e1.x + e2.x * e2.x + e3.x * e3.x;
            nr1 += e0.y * e0.y + e1.y * e1.y + e2.y * e2.y + e3.y * e3.y;
            nr2 += e0.z * e0.z + e1.z * e1.z + e2.z * e2.z + e3.z * e3.z;
            nr3 += e0.w * e0.w + e1.w * e1.w + e2.w * e2.w + e3.w * e3.w;
        }

        const float i0 = dot0 / fmaxf(sqrtf(nr0), EPS) * INV_TAU;
        const float i1 = dot1 / fmaxf(sqrtf(nr1), EPS) * INV_TAU;
        const float i2 = dot2 / fmaxf(sqrtf(nr2), EPS) * INV_TAU;
        const float i3 = dot3 / fmaxf(sqrtf(nr3), EPS) * INV_TAU;
        float esum = expf(i0) + expf(i1) + expf(i2) + expf(i3);
        float isum = i0 + i1 + i2 + i3;

#pragma unroll
        for (int off = 32; off > 0; off >>= 1) {
            esum += __shfl_down(esum, off);
            isum += __shfl_down(isum, off);
        }
        const int wid = t >> 6;
        const int lane = t & 63;
        if (lane == 0) { we[wid] = esum; wi[wid] = isum; }
        __syncthreads();
        if (t == 0) {
            float a = 0.f, b = 0.f;
#pragma unroll
            for (int w = 0; w < 16; ++w) { a += we[w]; b += wi[w]; }
            bpe[bid] = a;
            bpi[bid] = b;
        }
        __syncthreads();  // protect we/wi reuse by phase 4
    }

    // ---------------- phase 4: inter (blocks 0..7) ----------------
    if (bid < 8) {
        const int e = bid * 1024 + t;
        const int a = edges[e];
        const int b = edges[NEDGE + e];
        float dot = 0.0f;
#pragma unroll
        for (int c0 = 0; c0 < NCH; c0 += 4) {
            const float4 ma = *(const float4*)(meansn + a * NCH + c0);
            const float4 mb = *(const float4*)(meansn + b * NCH + c0);
            dot += ma.x * mb.x + ma.y * mb.y + ma.z * mb.z + ma.w * mb.w;
        }
        float ex = expf(dot * INV_TAU);
#pragma unroll
        for (int off = 32; off > 0; off >>= 1) ex += __shfl_down(ex, off);
        const int wid = t >> 6;
        const int lane = t & 63;
        if (lane == 0) we[wid] = ex;
        __syncthreads();
        if (t == 0) {
            float a2 = 0.f;
#pragma unroll
            for (int w = 0; w < 16; ++w) a2 += we[w];
            ipe[bid] = a2;
        }
    }
    grid.sync();

    // ---------------- phase 5: final (block 0) ----------------
    if (bid == 0) {
        float ev = (t < 256) ? bpe[t] : 0.0f;
        float iv = (t < 256) ? bpi[t] : 0.0f;
        if (t < 8) ev += ipe[t];
#pragma unroll
        for (int off = 32; off > 0; off >>= 1) {
            ev += __shfl_down(ev, off);
            iv += __shfl_down(iv, off);
        }
        const int wid = t >> 6;
        const int lane = t & 63;
        __syncthreads();  // we/wi reuse
        if (lane == 0) { we[wid] = ev; wi[wid] = iv; }
        __syncthreads();
        if (t == 0) {
            float E = 0.f, I = 0.f;
#pragma unroll
            for (int w = 0; w < 16; ++w) { E += we[w]; I += wi[w]; }
            out[0] = logf(E) - I * (1.0f / (float)N_PIX);
        }
    }
}

extern "C" void kernel_launch(void* const* d_in, const int* in_sizes, int n_in,
                              void* d_out, int out_size, void* d_ws, size_t ws_size,
                              hipStream_t stream) {
    (void)in_sizes; (void)n_in; (void)out_size; (void)ws_size;
    const float* emb = (const float*)d_in[0];   // (32, 1024*1024) channel-major
    const int* seg = (const int*)d_in[1];       // (1024*1024,)
    const int* edges = (const int*)d_in[2];     // (2, 8192)
    float* out = (float*)d_out;

    int* wsi = (int*)d_ws;
    float* wsf = (float*)d_ws;
    int* gsum_i = wsi + OFF_GSUMI;
    int* gcnt_i = wsi + OFF_GCNTI;
    float* meansn = wsf + OFF_MEANSN;
    float* bpe = wsf + OFF_BPE;
    float* bpi = wsf + OFF_BPI;
    float* ipe = wsf + OFF_IPE;

    void* args[] = {&emb, &seg, &edges, &gsum_i, &gcnt_i,
                    &meansn, &bpe, &bpi, &ipe, &out};
    hipLaunchCooperativeKernel((const void*)k_fused, dim3(256), dim3(1024),
                               args, 0, stream);
}